// Round 8
// baseline (768.635 us; speedup 1.0000x reference)
//
#include <hip/hip_runtime.h>
#include <math.h>

#define NNODES  100000
#define NEDGES  3200000
#define NGRAPHS 1024
#define NBLK    ((NNODES + 255) / 256)     // 391 scan blocks
#define NPART   8                          // one partition per XCD
#define PSTRIDE ((NNODES + NPART - 1) / NPART)   // 12500
#define CHUNK   8192
#define NCHUNKS ((NEDGES + CHUNK - 1) / CHUNK)   // 391 tasks per partition

typedef int iv4 __attribute__((ext_vector_type(4)));   // native vector for nt loads

// physical XCD id of the CU this wave runs on (gfx940+; HW-verified on gfx950)
__device__ __forceinline__ int xcc_id() {
    unsigned id;
    asm volatile("s_getreg_b32 %0, hwreg(HW_REG_XCC_ID)" : "=s"(id));
    return (int)(id & (NPART - 1));
}

// ---- bf16x2 pack/unpack (RNE) ----
__device__ __forceinline__ unsigned bf16pair(float a, float b) {
    unsigned ua = __float_as_uint(a), ub = __float_as_uint(b);
    ua += 0x7fffu + ((ua >> 16) & 1u);
    ub += 0x7fffu + ((ub >> 16) & 1u);
    return (ua >> 16) | (ub & 0xffff0000u);
}
__device__ __forceinline__ float bflo(unsigned u) { return __uint_as_float(u << 16); }
__device__ __forceinline__ float bfhi(unsigned u) { return __uint_as_float(u & 0xffff0000u); }

// ---------------- init ----------------

__global__ void zero4_kernel(int4* p, int nvec) {
    int i = blockIdx.x * blockDim.x + threadIdx.x;
    if (i < nvec) p[i] = make_int4(0, 0, 0, 0);
}

// XCD-pinned task-stealing histogram: task = (partition, chunk)
__global__ void hist_kernel(const int* __restrict__ dst, int* __restrict__ cnt,
                            int* __restrict__ taskctr) {
    int my = xcc_id();
    for (int pp = 0; pp < NPART; ++pp) {
        int p = (my + pp) & (NPART - 1);
        int lo = p * PSTRIDE, hi = lo + PSTRIDE;
        for (;;) {
            __shared__ int t_sh;
            if (threadIdx.x == 0) t_sh = atomicAdd(&taskctr[p], 1);
            __syncthreads();
            int t = t_sh;
            __syncthreads();
            if (t >= NCHUNKS) break;
            int beg = t * CHUNK;
            int end = beg + CHUNK; if (end > NEDGES) end = NEDGES;
            for (int e = beg + threadIdx.x * 4; e < end; e += 256 * 4) {
                iv4 d4 = __builtin_nontemporal_load((const iv4*)(dst + e));
                if (d4.x >= lo && d4.x < hi) atomicAdd(&cnt[d4.x], 1);
                if (d4.y >= lo && d4.y < hi) atomicAdd(&cnt[d4.y], 1);
                if (d4.z >= lo && d4.z < hi) atomicAdd(&cnt[d4.z], 1);
                if (d4.w >= lo && d4.w < hi) atomicAdd(&cnt[d4.w], 1);
            }
        }
    }
}

// dinv[n]=rsqrt(deg+1); xs[n][f]=x[n][f]*dinv (bf16x2 packed) — thread per float4
__global__ void dinvx_kernel(const int* __restrict__ cnt, const float4* __restrict__ x,
                             float* __restrict__ dinv, unsigned* __restrict__ xs) {
    int t = blockIdx.x * blockDim.x + threadIdx.x;
    if (t >= NNODES * 4) return;
    int n = t >> 2, q = t & 3;
    float di = rsqrtf((float)(cnt[n] + 1));
    if (q == 0) dinv[n] = di;
    float4 v = x[t];
    unsigned p0 = bf16pair(v.x * di, v.y * di);
    unsigned p1 = bf16pair(v.z * di, v.w * di);
    xs[n * 8 + q * 2]     = p0;
    xs[n * 8 + q * 2 + 1] = p1;
}

// ---------------- exclusive scan ----------------

__global__ void scanA_kernel(const int* __restrict__ cnt, int* __restrict__ part,
                             int* __restrict__ bsum) {
    __shared__ int s[256];
    int i = blockIdx.x * 256 + threadIdx.x;
    int v = (i < NNODES) ? cnt[i] : 0;
    s[threadIdx.x] = v;
    __syncthreads();
    for (int off = 1; off < 256; off <<= 1) {
        int t = (threadIdx.x >= off) ? s[threadIdx.x - off] : 0;
        __syncthreads();
        s[threadIdx.x] += t;
        __syncthreads();
    }
    int incl = s[threadIdx.x];
    if (i < NNODES) part[i] = incl - v;
    if (threadIdx.x == 255) bsum[blockIdx.x] = incl;
}

__global__ void scanB_kernel(const int* __restrict__ bsum, int* __restrict__ boff) {
    int lane = threadIdx.x;          // 64 lanes
    int run = 0;
    for (int base = 0; base < NBLK; base += 64) {
        int idx = base + lane;
        int own = (idx < NBLK) ? bsum[idx] : 0;
        int v = own;
        for (int off = 1; off < 64; off <<= 1) {
            int t = __shfl_up(v, off, 64);
            if (lane >= off) v += t;
        }
        if (idx < NBLK) boff[idx] = run + v - own;
        run += __shfl(v, 63, 64);
    }
}

__global__ void scanC_kernel(int* __restrict__ part, const int* __restrict__ boff,
                             int* __restrict__ rowptr, int* __restrict__ cursor) {
    int i = blockIdx.x * 256 + threadIdx.x;
    if (i < NNODES) {
        int v = part[i] + boff[blockIdx.x];
        rowptr[i] = v;
        cursor[i] = v;
    }
}

// ---------------- CSR fill (XCD-pinned task-stealing, nt edge reads) ----------------

__global__ void csr_fill_kernel(const int* __restrict__ src, const int* __restrict__ dst,
                                int* __restrict__ cursor, int* __restrict__ entries,
                                int* __restrict__ taskctr) {
    int my = xcc_id();
    for (int pp = 0; pp < NPART; ++pp) {
        int p = (my + pp) & (NPART - 1);
        int lo = p * PSTRIDE, hi = lo + PSTRIDE;
        for (;;) {
            __shared__ int t_sh;
            if (threadIdx.x == 0) t_sh = atomicAdd(&taskctr[p], 1);
            __syncthreads();
            int t = t_sh;
            __syncthreads();
            if (t >= NCHUNKS) break;
            int beg = t * CHUNK;
            int end = beg + CHUNK; if (end > NEDGES) end = NEDGES;
            for (int e = beg + threadIdx.x * 4; e < end; e += 256 * 4) {
                iv4 d4 = __builtin_nontemporal_load((const iv4*)(dst + e));
                iv4 s4 = __builtin_nontemporal_load((const iv4*)(src + e));
                if (d4.x >= lo && d4.x < hi) entries[atomicAdd(&cursor[d4.x], 1)] = s4.x;
                if (d4.y >= lo && d4.y < hi) entries[atomicAdd(&cursor[d4.y], 1)] = s4.y;
                if (d4.z >= lo && d4.z < hi) entries[atomicAdd(&cursor[d4.z], 1)] = s4.z;
                if (d4.w >= lo && d4.w < hi) entries[atomicAdd(&cursor[d4.w], 1)] = s4.w;
            }
        }
    }
}

// ---------------- gather 1 (bf16, 8 lanes/node, 2 feats/lane) ----------------

__global__ void gather1_kernel(const int* __restrict__ entries, const int* __restrict__ rowptr,
                               const int* __restrict__ rowend, const float* __restrict__ dinv,
                               const unsigned* __restrict__ xs, unsigned* __restrict__ ax) {
    int t = blockIdx.x * blockDim.x + threadIdx.x;
    int n = t >> 3, lane = t & 7;
    int beg = rowptr[n], end = rowend[n];
    unsigned self = xs[n * 8 + lane];
    float a0 = bflo(self), a1 = bfhi(self);
    for (int base = beg; base < end; base += 8) {
        int m = end - base; if (m > 8) m = 8;
        int s = (lane < m) ? __builtin_nontemporal_load(entries + base + lane) : 0;
        if (m == 8) {
#pragma unroll
            for (int j = 0; j < 8; ++j) {
                unsigned v = xs[__shfl(s, j, 8) * 8 + lane];
                a0 += bflo(v); a1 += bfhi(v);
            }
        } else {
            for (int j = 0; j < m; ++j) {
                unsigned v = xs[__shfl(s, j, 8) * 8 + lane];
                a0 += bflo(v); a1 += bfhi(v);
            }
        }
    }
    float di = dinv[n];
    ax[n * 8 + lane] = bf16pair(a0 * di, a1 * di);
}

// ---------------- fused node MLP: ax -> relu(axW1+b1) -> (h1W2)*dinv -> hm2s ----------------
// 16 nodes/block, 16 lanes/node

__global__ void mlp_kernel(const unsigned* __restrict__ axb, const float* __restrict__ W1,
                           const float* __restrict__ b1, const float* __restrict__ W2,
                           const float* __restrict__ dinv, unsigned* __restrict__ hm2s) {
    __shared__ float w1[16 * 64];
    __shared__ float w2[64 * 32];
    __shared__ float bb1[64];
    __shared__ float axs[16][17];   // +1 pad
    __shared__ float h1s[16][65];   // +1 pad
    int tid = threadIdx.x;
    for (int i = tid; i < 16 * 64; i += 256) w1[i] = W1[i];
    for (int i = tid; i < 64 * 32; i += 256) w2[i] = W2[i];
    if (tid < 64) bb1[tid] = b1[tid];

    int nl = tid >> 4, lane = tid & 15;
    int n = blockIdx.x * 16 + nl;

    if (lane < 8) {
        unsigned v = axb[n * 8 + lane];
        axs[nl][lane * 2]     = bflo(v);
        axs[nl][lane * 2 + 1] = bfhi(v);
    }
    __syncthreads();

    {
        int j0 = lane * 4;
        float h0 = bb1[j0], h1v = bb1[j0 + 1], h2 = bb1[j0 + 2], h3 = bb1[j0 + 3];
#pragma unroll
        for (int k = 0; k < 16; ++k) {
            float a = axs[nl][k];
            const float* wr = w1 + k * 64 + j0;
            h0 += a * wr[0]; h1v += a * wr[1]; h2 += a * wr[2]; h3 += a * wr[3];
        }
        h1s[nl][j0]     = fmaxf(h0, 0.f);
        h1s[nl][j0 + 1] = fmaxf(h1v, 0.f);
        h1s[nl][j0 + 2] = fmaxf(h2, 0.f);
        h1s[nl][j0 + 3] = fmaxf(h3, 0.f);
    }
    __syncthreads();

    {
        int j0 = lane * 2;
        float c0 = 0.f, c1 = 0.f;
#pragma unroll
        for (int k = 0; k < 64; ++k) {
            float hv = h1s[nl][k];
            c0 += hv * w2[k * 32 + j0];
            c1 += hv * w2[k * 32 + j0 + 1];
        }
        float di = dinv[n];
        hm2s[n * 16 + lane] = bf16pair(c0 * di, c1 * di);
    }
}

// ---------------- gather 2 + pool (bf16, 16 lanes/node, 2 feats/lane) ----------------

__global__ void gather2_pool_kernel(const int* __restrict__ entries, const int* __restrict__ rowptr,
                                    const int* __restrict__ rowend, const float* __restrict__ dinv,
                                    const unsigned* __restrict__ hm2s, const float* __restrict__ b2,
                                    const int* __restrict__ batch,
                                    float* __restrict__ psum, float* __restrict__ pcnt) {
    int t = blockIdx.x * blockDim.x + threadIdx.x;
    int n = t >> 4, lane = t & 15;
    int beg = rowptr[n], end = rowend[n];
    unsigned self = hm2s[n * 16 + lane];
    float a0 = bflo(self), a1 = bfhi(self);
    for (int base = beg; base < end; base += 16) {
        int m = end - base; if (m > 16) m = 16;
        int s = (lane < m) ? __builtin_nontemporal_load(entries + base + lane) : 0;
        if (m == 16) {
#pragma unroll
            for (int j = 0; j < 16; ++j) {
                unsigned v = hm2s[__shfl(s, j, 16) * 16 + lane];
                a0 += bflo(v); a1 += bfhi(v);
            }
        } else {
            for (int j = 0; j < m; ++j) {
                unsigned v = hm2s[__shfl(s, j, 16) * 16 + lane];
                a0 += bflo(v); a1 += bfhi(v);
            }
        }
    }
    float di = dinv[n];
    int j0 = lane * 2;
    float v0 = fmaxf(a0 * di + b2[j0], 0.f);
    float v1 = fmaxf(a1 * di + b2[j0 + 1], 0.f);
    int g = batch[n];
    atomicAdd(&psum[g * 32 + j0], v0);
    atomicAdd(&psum[g * 32 + j0 + 1], v1);
    if (lane == 0) atomicAdd(&pcnt[g], 1.0f);
}

// ---------------- head ----------------

__global__ void head_kernel(const float* __restrict__ psum, const float* __restrict__ pcnt,
                            const float* __restrict__ fc1W, const float* __restrict__ fc1b,
                            const float* __restrict__ fc2W, const float* __restrict__ fc2b,
                            float* __restrict__ out) {
    int g = blockIdx.x * blockDim.x + threadIdx.x;
    if (g >= NGRAPHS) return;
    float inv = 1.0f / fmaxf(pcnt[g], 1.0f);
    float gv[32];
#pragma unroll
    for (int k = 0; k < 32; ++k) gv[k] = psum[g * 32 + k] * inv;
    float o = fc2b[0];
#pragma unroll
    for (int j = 0; j < 16; ++j) {
        float h = fc1b[j];
#pragma unroll
        for (int k = 0; k < 32; ++k) h += gv[k] * fc1W[k * 16 + j];
        h = fmaxf(h, 0.f);
        o += h * fc2W[j];
    }
    out[g] = 1.0f / (1.0f + expf(-o));
}

// ---------------- launch ----------------

extern "C" void kernel_launch(void* const* d_in, const int* in_sizes, int n_in,
                              void* d_out, int out_size, void* d_ws, size_t ws_size,
                              hipStream_t stream) {
    const float* x    = (const float*)d_in[0];
    const int*   ei   = (const int*)d_in[1];
    const int*   batch= (const int*)d_in[2];
    const float* W1   = (const float*)d_in[3];
    const float* b1   = (const float*)d_in[4];
    const float* W2   = (const float*)d_in[5];
    const float* b2   = (const float*)d_in[6];
    const float* fc1W = (const float*)d_in[7];
    const float* fc1b = (const float*)d_in[8];
    const float* fc2W = (const float*)d_in[9];
    const float* fc2b = (const float*)d_in[10];
    float* out = (float*)d_out;

    const int* src = ei;
    const int* dst = ei + NEDGES;

    char* wsb = (char*)d_ws;
    int*      cnt    = (int*)wsb;                 // 400000 B  } zeroed span
    float*    psum   = (float*)(wsb + 400000);    // 131072 B  }
    float*    pcnt   = (float*)(wsb + 531072);    // 4096 B    }
    int*      tcA    = (int*)(wsb + 535168);      // 32 B      }  hist task counters
    int*      tcB    = (int*)(wsb + 535200);      // 32 B      }  fill task counters
    float*    dinv   = (float*)(wsb + 535552);    // 400000 B
    int*      rowptr = (int*)(wsb + 935936);      // 400000 B
    int*      cursor = (int*)(wsb + 1336320);     // 400000 B
    int*      bsum   = (int*)(wsb + 1736704);     // ~2 KB
    int*      boff   = (int*)(wsb + 1738752);     // ~2 KB
    int*      entries= (int*)(wsb + 1740800);     // 12.8 MB
    unsigned* xs     = (unsigned*)(wsb + 14541312);  // 3.2 MB  (bf16x2)
    unsigned* ax     = (unsigned*)(wsb + 17741312);  // 3.2 MB
    unsigned* hm2s   = (unsigned*)(wsb + 20941312);  // 6.4 MB  (ends ~27.4 MB)

    const int B = 256;
    // zero cnt+psum+pcnt+taskctrs: 535232 B = 33452 int4
    zero4_kernel<<<(33452 + B - 1) / B, B, 0, stream>>>((int4*)cnt, 33452);

    hist_kernel<<<1024, B, 0, stream>>>(dst, cnt, tcA);
    dinvx_kernel<<<(NNODES * 4 + B - 1) / B, B, 0, stream>>>(cnt, (const float4*)x, dinv, xs);

    scanA_kernel<<<NBLK, 256, 0, stream>>>(cnt, rowptr, bsum);
    scanB_kernel<<<1, 64, 0, stream>>>(bsum, boff);
    scanC_kernel<<<NBLK, 256, 0, stream>>>(rowptr, boff, rowptr, cursor);

    csr_fill_kernel<<<1024, B, 0, stream>>>(src, dst, cursor, entries, tcB);

    gather1_kernel<<<NNODES * 8 / B, B, 0, stream>>>(entries, rowptr, cursor, dinv, xs, ax);
    mlp_kernel<<<NNODES / 16, B, 0, stream>>>(ax, W1, b1, W2, dinv, hm2s);
    gather2_pool_kernel<<<NNODES * 16 / B, B, 0, stream>>>(entries, rowptr, cursor, dinv,
                                                           hm2s, b2, batch, psum, pcnt);
    head_kernel<<<(NGRAPHS + B - 1) / B, B, 0, stream>>>(psum, pcnt, fc1W, fc1b, fc2W, fc2b, out);
}

// Round 9
// 651.495 us; speedup vs baseline: 1.1798x; 1.1798x over previous
//
#include <hip/hip_runtime.h>
#include <math.h>

#define NNODES  100000
#define NEDGES  3200000
#define NGRAPHS 1024
#define NBLK    ((NNODES + 255) / 256)     // 391 scan blocks
#define NPART   4                          // dst partitions (L2-window sized)
#define PSTRIDE ((NNODES + NPART - 1) / NPART)   // 25000
#define CHUNK   16384
#define NCHUNKS ((NEDGES + CHUNK - 1) / CHUNK)   // 196

typedef int iv4 __attribute__((ext_vector_type(4)));   // native vector for nt loads

// ---- bf16x2 pack/unpack (RNE) ----
__device__ __forceinline__ unsigned bf16pair(float a, float b) {
    unsigned ua = __float_as_uint(a), ub = __float_as_uint(b);
    ua += 0x7fffu + ((ua >> 16) & 1u);
    ub += 0x7fffu + ((ub >> 16) & 1u);
    return (ua >> 16) | (ub & 0xffff0000u);
}
__device__ __forceinline__ float bflo(unsigned u) { return __uint_as_float(u << 16); }
__device__ __forceinline__ float bfhi(unsigned u) { return __uint_as_float(u & 0xffff0000u); }

// ---------------- init ----------------

__global__ void zero4_kernel(int4* p, int nvec) {
    int i = blockIdx.x * blockDim.x + threadIdx.x;
    if (i < nvec) p[i] = make_int4(0, 0, 0, 0);
}

// dst-partitioned in-degree histogram (nt edge reads)
__global__ void hist_kernel(const int* __restrict__ dst, int* __restrict__ cnt) {
    int p = blockIdx.x & (NPART - 1);
    int c = blockIdx.x / NPART;
    int lo = p * PSTRIDE, hi = lo + PSTRIDE;
    int beg = c * CHUNK;
    int end = beg + CHUNK; if (end > NEDGES) end = NEDGES;
    for (int e = beg + threadIdx.x * 4; e < end; e += 256 * 4) {
        iv4 d4 = __builtin_nontemporal_load((const iv4*)(dst + e));
        if (d4.x >= lo && d4.x < hi) atomicAdd(&cnt[d4.x], 1);
        if (d4.y >= lo && d4.y < hi) atomicAdd(&cnt[d4.y], 1);
        if (d4.z >= lo && d4.z < hi) atomicAdd(&cnt[d4.z], 1);
        if (d4.w >= lo && d4.w < hi) atomicAdd(&cnt[d4.w], 1);
    }
}

// ---------------- scan A (fused with dinv + xs prescale) ----------------

__global__ void scanA_kernel(const int* __restrict__ cnt, const float4* __restrict__ x,
                             int* __restrict__ part, int* __restrict__ bsum,
                             float* __restrict__ dinv, unsigned* __restrict__ xs) {
    __shared__ int s[256];
    int i = blockIdx.x * 256 + threadIdx.x;
    int v = (i < NNODES) ? cnt[i] : 0;
    s[threadIdx.x] = v;
    __syncthreads();
    for (int off = 1; off < 256; off <<= 1) {
        int t = (threadIdx.x >= off) ? s[threadIdx.x - off] : 0;
        __syncthreads();
        s[threadIdx.x] += t;
        __syncthreads();
    }
    int incl = s[threadIdx.x];
    if (i < NNODES) {
        part[i] = incl - v;                 // exclusive within block
        float di = rsqrtf((float)(v + 1));  // +1 self-loop
        dinv[i] = di;
        float4 a = x[i * 4], b = x[i * 4 + 1], c = x[i * 4 + 2], d = x[i * 4 + 3];
        xs[i * 8 + 0] = bf16pair(a.x * di, a.y * di);
        xs[i * 8 + 1] = bf16pair(a.z * di, a.w * di);
        xs[i * 8 + 2] = bf16pair(b.x * di, b.y * di);
        xs[i * 8 + 3] = bf16pair(b.z * di, b.w * di);
        xs[i * 8 + 4] = bf16pair(c.x * di, c.y * di);
        xs[i * 8 + 5] = bf16pair(c.z * di, c.w * di);
        xs[i * 8 + 6] = bf16pair(d.x * di, d.y * di);
        xs[i * 8 + 7] = bf16pair(d.z * di, d.w * di);
    }
    if (threadIdx.x == 255) bsum[blockIdx.x] = incl;
}

__global__ void scanB_kernel(const int* __restrict__ bsum, int* __restrict__ boff) {
    int lane = threadIdx.x;          // 64 lanes
    int run = 0;
    for (int base = 0; base < NBLK; base += 64) {
        int idx = base + lane;
        int own = (idx < NBLK) ? bsum[idx] : 0;
        int v = own;
        for (int off = 1; off < 64; off <<= 1) {
            int t = __shfl_up(v, off, 64);
            if (lane >= off) v += t;
        }
        if (idx < NBLK) boff[idx] = run + v - own;
        run += __shfl(v, 63, 64);
    }
}

__global__ void scanC_kernel(int* __restrict__ part, const int* __restrict__ boff,
                             int* __restrict__ rowptr, int* __restrict__ cursor) {
    int i = blockIdx.x * 256 + threadIdx.x;
    if (i < NNODES) {
        int v = part[i] + boff[blockIdx.x];
        rowptr[i] = v;
        cursor[i] = v;
    }
}

// ---------------- CSR fill (dst-partitioned, nt loads, nt scattered stores) ----------------

__global__ void csr_fill_kernel(const int* __restrict__ src, const int* __restrict__ dst,
                                int* __restrict__ cursor, int* __restrict__ entries) {
    int p = blockIdx.x & (NPART - 1);
    int c = blockIdx.x / NPART;
    int lo = p * PSTRIDE, hi = lo + PSTRIDE;
    int beg = c * CHUNK;
    int end = beg + CHUNK; if (end > NEDGES) end = NEDGES;
    for (int e = beg + threadIdx.x * 4; e < end; e += 256 * 4) {
        iv4 d4 = __builtin_nontemporal_load((const iv4*)(dst + e));
        iv4 s4 = __builtin_nontemporal_load((const iv4*)(src + e));
        if (d4.x >= lo && d4.x < hi) __builtin_nontemporal_store(s4.x, entries + atomicAdd(&cursor[d4.x], 1));
        if (d4.y >= lo && d4.y < hi) __builtin_nontemporal_store(s4.y, entries + atomicAdd(&cursor[d4.y], 1));
        if (d4.z >= lo && d4.z < hi) __builtin_nontemporal_store(s4.z, entries + atomicAdd(&cursor[d4.z], 1));
        if (d4.w >= lo && d4.w < hi) __builtin_nontemporal_store(s4.w, entries + atomicAdd(&cursor[d4.w], 1));
    }
}

// ---------------- gather 1 (bf16, 8 lanes/node, 2 feats/lane) ----------------

__global__ void gather1_kernel(const int* __restrict__ entries, const int* __restrict__ rowptr,
                               const int* __restrict__ rowend, const float* __restrict__ dinv,
                               const unsigned* __restrict__ xs, unsigned* __restrict__ ax) {
    int t = blockIdx.x * blockDim.x + threadIdx.x;
    int n = t >> 3, lane = t & 7;
    int beg = rowptr[n], end = rowend[n];
    unsigned self = xs[n * 8 + lane];
    float a0 = bflo(self), a1 = bfhi(self);
    for (int base = beg; base < end; base += 8) {
        int m = end - base; if (m > 8) m = 8;
        int s = (lane < m) ? __builtin_nontemporal_load(entries + base + lane) : 0;
        if (m == 8) {
#pragma unroll
            for (int j = 0; j < 8; ++j) {
                unsigned v = xs[__shfl(s, j, 8) * 8 + lane];
                a0 += bflo(v); a1 += bfhi(v);
            }
        } else {
            for (int j = 0; j < m; ++j) {
                unsigned v = xs[__shfl(s, j, 8) * 8 + lane];
                a0 += bflo(v); a1 += bfhi(v);
            }
        }
    }
    float di = dinv[n];
    ax[n * 8 + lane] = bf16pair(a0 * di, a1 * di);
}

// ---------------- fused node MLP: ax -> relu(axW1+b1) -> (h1W2)*dinv -> hm2s ----------------
// 16 nodes/block, 16 lanes/node

__global__ void mlp_kernel(const unsigned* __restrict__ axb, const float* __restrict__ W1,
                           const float* __restrict__ b1, const float* __restrict__ W2,
                           const float* __restrict__ dinv, unsigned* __restrict__ hm2s) {
    __shared__ float w1[16 * 64];
    __shared__ float w2[64 * 32];
    __shared__ float bb1[64];
    __shared__ float axs[16][17];   // +1 pad
    __shared__ float h1s[16][65];   // +1 pad
    int tid = threadIdx.x;
    for (int i = tid; i < 16 * 64; i += 256) w1[i] = W1[i];
    for (int i = tid; i < 64 * 32; i += 256) w2[i] = W2[i];
    if (tid < 64) bb1[tid] = b1[tid];

    int nl = tid >> 4, lane = tid & 15;
    int n = blockIdx.x * 16 + nl;

    if (lane < 8) {
        unsigned v = axb[n * 8 + lane];
        axs[nl][lane * 2]     = bflo(v);
        axs[nl][lane * 2 + 1] = bfhi(v);
    }
    __syncthreads();

    {
        int j0 = lane * 4;
        float h0 = bb1[j0], h1v = bb1[j0 + 1], h2 = bb1[j0 + 2], h3 = bb1[j0 + 3];
#pragma unroll
        for (int k = 0; k < 16; ++k) {
            float a = axs[nl][k];
            const float* wr = w1 + k * 64 + j0;
            h0 += a * wr[0]; h1v += a * wr[1]; h2 += a * wr[2]; h3 += a * wr[3];
        }
        h1s[nl][j0]     = fmaxf(h0, 0.f);
        h1s[nl][j0 + 1] = fmaxf(h1v, 0.f);
        h1s[nl][j0 + 2] = fmaxf(h2, 0.f);
        h1s[nl][j0 + 3] = fmaxf(h3, 0.f);
    }
    __syncthreads();

    {
        int j0 = lane * 2;
        float c0 = 0.f, c1 = 0.f;
#pragma unroll
        for (int k = 0; k < 64; ++k) {
            float hv = h1s[nl][k];
            c0 += hv * w2[k * 32 + j0];
            c1 += hv * w2[k * 32 + j0 + 1];
        }
        float di = dinv[n];
        hm2s[n * 16 + lane] = bf16pair(c0 * di, c1 * di);
    }
}

// ---------------- gather 2 + pool (bf16, 16 lanes/node, 2 feats/lane) ----------------

__global__ void gather2_pool_kernel(const int* __restrict__ entries, const int* __restrict__ rowptr,
                                    const int* __restrict__ rowend, const float* __restrict__ dinv,
                                    const unsigned* __restrict__ hm2s, const float* __restrict__ b2,
                                    const int* __restrict__ batch,
                                    float* __restrict__ psum, float* __restrict__ pcnt) {
    int t = blockIdx.x * blockDim.x + threadIdx.x;
    int n = t >> 4, lane = t & 15;
    int beg = rowptr[n], end = rowend[n];
    unsigned self = hm2s[n * 16 + lane];
    float a0 = bflo(self), a1 = bfhi(self);
    for (int base = beg; base < end; base += 16) {
        int m = end - base; if (m > 16) m = 16;
        int s = (lane < m) ? __builtin_nontemporal_load(entries + base + lane) : 0;
        if (m == 16) {
#pragma unroll
            for (int j = 0; j < 16; ++j) {
                unsigned v = hm2s[__shfl(s, j, 16) * 16 + lane];
                a0 += bflo(v); a1 += bfhi(v);
            }
        } else {
            for (int j = 0; j < m; ++j) {
                unsigned v = hm2s[__shfl(s, j, 16) * 16 + lane];
                a0 += bflo(v); a1 += bfhi(v);
            }
        }
    }
    float di = dinv[n];
    int j0 = lane * 2;
    float v0 = fmaxf(a0 * di + b2[j0], 0.f);
    float v1 = fmaxf(a1 * di + b2[j0 + 1], 0.f);
    int g = batch[n];
    atomicAdd(&psum[g * 32 + j0], v0);
    atomicAdd(&psum[g * 32 + j0 + 1], v1);
    if (lane == 0) atomicAdd(&pcnt[g], 1.0f);
}

// ---------------- head ----------------

__global__ void head_kernel(const float* __restrict__ psum, const float* __restrict__ pcnt,
                            const float* __restrict__ fc1W, const float* __restrict__ fc1b,
                            const float* __restrict__ fc2W, const float* __restrict__ fc2b,
                            float* __restrict__ out) {
    int g = blockIdx.x * blockDim.x + threadIdx.x;
    if (g >= NGRAPHS) return;
    float inv = 1.0f / fmaxf(pcnt[g], 1.0f);
    float gv[32];
#pragma unroll
    for (int k = 0; k < 32; ++k) gv[k] = psum[g * 32 + k] * inv;
    float o = fc2b[0];
#pragma unroll
    for (int j = 0; j < 16; ++j) {
        float h = fc1b[j];
#pragma unroll
        for (int k = 0; k < 32; ++k) h += gv[k] * fc1W[k * 16 + j];
        h = fmaxf(h, 0.f);
        o += h * fc2W[j];
    }
    out[g] = 1.0f / (1.0f + expf(-o));
}

// ---------------- launch ----------------

extern "C" void kernel_launch(void* const* d_in, const int* in_sizes, int n_in,
                              void* d_out, int out_size, void* d_ws, size_t ws_size,
                              hipStream_t stream) {
    const float* x    = (const float*)d_in[0];
    const int*   ei   = (const int*)d_in[1];
    const int*   batch= (const int*)d_in[2];
    const float* W1   = (const float*)d_in[3];
    const float* b1   = (const float*)d_in[4];
    const float* W2   = (const float*)d_in[5];
    const float* b2   = (const float*)d_in[6];
    const float* fc1W = (const float*)d_in[7];
    const float* fc1b = (const float*)d_in[8];
    const float* fc2W = (const float*)d_in[9];
    const float* fc2b = (const float*)d_in[10];
    float* out = (float*)d_out;

    const int* src = ei;
    const int* dst = ei + NEDGES;

    char* wsb = (char*)d_ws;
    int*      cnt    = (int*)wsb;                 // 400000 B  } zeroed span
    float*    psum   = (float*)(wsb + 400000);    // 131072 B  }
    float*    pcnt   = (float*)(wsb + 531072);    // 4096 B    }
    float*    dinv   = (float*)(wsb + 535552);    // 400000 B
    int*      rowptr = (int*)(wsb + 935936);      // 400000 B
    int*      cursor = (int*)(wsb + 1336320);     // 400000 B
    int*      bsum   = (int*)(wsb + 1736704);     // ~2 KB
    int*      boff   = (int*)(wsb + 1738752);     // ~2 KB
    int*      entries= (int*)(wsb + 1740800);     // 12.8 MB
    unsigned* xs     = (unsigned*)(wsb + 14541312);  // 3.2 MB  (bf16x2)
    unsigned* ax     = (unsigned*)(wsb + 17741312);  // 3.2 MB
    unsigned* hm2s   = (unsigned*)(wsb + 20941312);  // 6.4 MB  (ends ~27.4 MB)

    const int B = 256;
    // zero cnt+psum+pcnt: 535168 B = 33448 int4
    zero4_kernel<<<(33448 + B - 1) / B, B, 0, stream>>>((int4*)cnt, 33448);

    hist_kernel<<<NCHUNKS * NPART, B, 0, stream>>>(dst, cnt);

    scanA_kernel<<<NBLK, 256, 0, stream>>>(cnt, (const float4*)x, rowptr, bsum, dinv, xs);
    scanB_kernel<<<1, 64, 0, stream>>>(bsum, boff);
    scanC_kernel<<<NBLK, 256, 0, stream>>>(rowptr, boff, rowptr, cursor);

    csr_fill_kernel<<<NCHUNKS * NPART, B, 0, stream>>>(src, dst, cursor, entries);

    gather1_kernel<<<NNODES * 8 / B, B, 0, stream>>>(entries, rowptr, cursor, dinv, xs, ax);
    mlp_kernel<<<NNODES / 16, B, 0, stream>>>(ax, W1, b1, W2, dinv, hm2s);
    gather2_pool_kernel<<<NNODES * 16 / B, B, 0, stream>>>(entries, rowptr, cursor, dinv,
                                                           hm2s, b2, batch, psum, pcnt);
    head_kernel<<<(NGRAPHS + B - 1) / B, B, 0, stream>>>(psum, pcnt, fc1W, fc1b, fc2W, fc2b, out);
}

// Round 10
// 405.045 us; speedup vs baseline: 1.8977x; 1.6085x over previous
//
#include <hip/hip_runtime.h>
#include <math.h>

#define NNODES  100000
#define NEDGES  3200000
#define NGRAPHS 1024
#define BNODES  196                              // nodes per bucket
#define NBUCK   ((NNODES + BNODES - 1) / BNODES) // 511
#define SCAP    12288                            // staging capacity per bucket (mean 6272, +76 sigma)
#define CHUNK   8192
#define NCHUNKS ((NEDGES + CHUNK - 1) / CHUNK)   // 391

typedef int iv4 __attribute__((ext_vector_type(4)));

// ---- bf16x2 pack/unpack (RNE) ----
__device__ __forceinline__ unsigned bf16pair(float a, float b) {
    unsigned ua = __float_as_uint(a), ub = __float_as_uint(b);
    ua += 0x7fffu + ((ua >> 16) & 1u);
    ub += 0x7fffu + ((ub >> 16) & 1u);
    return (ua >> 16) | (ub & 0xffff0000u);
}
__device__ __forceinline__ float bflo(unsigned u) { return __uint_as_float(u << 16); }
__device__ __forceinline__ float bfhi(unsigned u) { return __uint_as_float(u & 0xffff0000u); }

// ---------------- init ----------------

__global__ void zero4_kernel(int4* p, int nvec) {
    int i = blockIdx.x * blockDim.x + threadIdx.x;
    if (i < nvec) p[i] = make_int4(0, 0, 0, 0);
}

// ---------------- binA: coarse bucket sort of edges (coalesced staging writes) ----------------
// stage[b*SCAP + slot] = src | (dst - b*BNODES) << 17

__global__ void binA_kernel(const int* __restrict__ src, const int* __restrict__ dst,
                            int* __restrict__ bucketCur, int* __restrict__ stage) {
    __shared__ int lcnt[NBUCK + 1];
    int beg = blockIdx.x * CHUNK;
    int end = beg + CHUNK; if (end > NEDGES) end = NEDGES;
    for (int i = threadIdx.x; i < NBUCK; i += 256) lcnt[i] = 0;
    __syncthreads();
    // phase 1: count per bucket
    for (int e = beg + threadIdx.x * 4; e < end; e += 1024) {
        iv4 d4 = __builtin_nontemporal_load((const iv4*)(dst + e));
        atomicAdd(&lcnt[d4.x / BNODES], 1);
        atomicAdd(&lcnt[d4.y / BNODES], 1);
        atomicAdd(&lcnt[d4.z / BNODES], 1);
        atomicAdd(&lcnt[d4.w / BNODES], 1);
    }
    __syncthreads();
    // reserve contiguous sub-range per bucket; lcnt becomes the running cursor
    for (int b = threadIdx.x; b < NBUCK; b += 256) {
        int c = lcnt[b];
        lcnt[b] = (c > 0) ? atomicAdd(&bucketCur[b], c) : 0;
    }
    __syncthreads();
    // phase 2: place packed words
    for (int e = beg + threadIdx.x * 4; e < end; e += 1024) {
        iv4 d4 = __builtin_nontemporal_load((const iv4*)(dst + e));
        iv4 s4 = __builtin_nontemporal_load((const iv4*)(src + e));
        int b0 = d4.x / BNODES, b1 = d4.y / BNODES, b2 = d4.z / BNODES, b3 = d4.w / BNODES;
        stage[b0 * SCAP + atomicAdd(&lcnt[b0], 1)] = s4.x | ((d4.x - b0 * BNODES) << 17);
        stage[b1 * SCAP + atomicAdd(&lcnt[b1], 1)] = s4.y | ((d4.y - b1 * BNODES) << 17);
        stage[b2 * SCAP + atomicAdd(&lcnt[b2], 1)] = s4.z | ((d4.z - b2 * BNODES) << 17);
        stage[b3 * SCAP + atomicAdd(&lcnt[b3], 1)] = s4.w | ((d4.w - b3 * BNODES) << 17);
    }
}

// ---------------- scanE: exclusive scan over bucket counts ----------------

__global__ void scanE_kernel(const int* __restrict__ bucketCur, int* __restrict__ ebase) {
    int lane = threadIdx.x;          // 64 lanes
    int run = 0;
    for (int base = 0; base < NBUCK; base += 64) {
        int idx = base + lane;
        int own = (idx < NBUCK) ? bucketCur[idx] : 0;
        int v = own;
        for (int off = 1; off < 64; off <<= 1) {
            int t = __shfl_up(v, off, 64);
            if (lane >= off) v += t;
        }
        if (idx < NBUCK) ebase[idx] = run + v - own;
        run += __shfl(v, 63, 64);
    }
}

// ---------------- binB: per-bucket fine sort + rowptr/rowend/dinv/xs ----------------

__global__ void binB_kernel(const int* __restrict__ bucketCur, const int* __restrict__ ebase,
                            const int* __restrict__ stage, const float2* __restrict__ x,
                            int* __restrict__ entries, int* __restrict__ rowptr,
                            int* __restrict__ rowend, float* __restrict__ dinv,
                            unsigned* __restrict__ xs) {
    __shared__ int s[256];        // hist then inclusive-scan workspace
    __shared__ int ncur[256];     // scatter cursors
    __shared__ float ndinv[256];
    int b = blockIdx.x;
    int cntE = bucketCur[b];
    int eb = ebase[b];
    int nlo = b * BNODES;
    int nn = NNODES - nlo; if (nn > BNODES) nn = BNODES;
    int sb = b * SCAP;
    int tid = threadIdx.x;

    s[tid] = 0;
    __syncthreads();
    for (int e = tid; e < cntE; e += 256) {
        unsigned w = (unsigned)stage[sb + e];
        atomicAdd(&s[w >> 17], 1);
    }
    __syncthreads();
    int v = s[tid];
    // block-wide Hillis-Steele inclusive scan on s[256]
    for (int off = 1; off < 256; off <<= 1) {
        int t = (tid >= off) ? s[tid - off] : 0;
        __syncthreads();
        s[tid] += t;
        __syncthreads();
    }
    int excl = s[tid] - v;
    ncur[tid] = excl;
    if (tid < nn) {
        rowptr[nlo + tid] = eb + excl;
        rowend[nlo + tid] = eb + excl + v;
        float di = rsqrtf((float)(v + 1));   // +1 self-loop
        dinv[nlo + tid] = di;
        ndinv[tid] = di;
    }
    __syncthreads();
    // xs prescale for this bucket's nodes (coalesced)
    for (int i = tid; i < nn * 8; i += 256) {
        int node = i >> 3, w = i & 7;
        float2 v2 = x[(size_t)(nlo + node) * 8 + w];
        float di = ndinv[node];
        xs[(nlo + node) * 8 + w] = bf16pair(v2.x * di, v2.y * di);
    }
    // fine scatter into the block-private L2-resident entries window
    for (int e = tid; e < cntE; e += 256) {
        unsigned w = (unsigned)stage[sb + e];
        int dl = w >> 17;
        int slot = atomicAdd(&ncur[dl], 1);
        entries[eb + slot] = (int)(w & 0x1FFFFu);
    }
}

// ---------------- gather 1 (bf16, 8 lanes/node, 2 feats/lane) ----------------

__global__ void gather1_kernel(const int* __restrict__ entries, const int* __restrict__ rowptr,
                               const int* __restrict__ rowend, const float* __restrict__ dinv,
                               const unsigned* __restrict__ xs, unsigned* __restrict__ ax) {
    int t = blockIdx.x * blockDim.x + threadIdx.x;
    int n = t >> 3, lane = t & 7;
    int beg = rowptr[n], end = rowend[n];
    unsigned self = xs[n * 8 + lane];
    float a0 = bflo(self), a1 = bfhi(self);
    for (int base = beg; base < end; base += 8) {
        int m = end - base; if (m > 8) m = 8;
        int s = (lane < m) ? __builtin_nontemporal_load(entries + base + lane) : 0;
        if (m == 8) {
#pragma unroll
            for (int j = 0; j < 8; ++j) {
                unsigned v = xs[__shfl(s, j, 8) * 8 + lane];
                a0 += bflo(v); a1 += bfhi(v);
            }
        } else {
            for (int j = 0; j < m; ++j) {
                unsigned v = xs[__shfl(s, j, 8) * 8 + lane];
                a0 += bflo(v); a1 += bfhi(v);
            }
        }
    }
    float di = dinv[n];
    ax[n * 8 + lane] = bf16pair(a0 * di, a1 * di);
}

// ---------------- fused node MLP ----------------

__global__ void mlp_kernel(const unsigned* __restrict__ axb, const float* __restrict__ W1,
                           const float* __restrict__ b1, const float* __restrict__ W2,
                           const float* __restrict__ dinv, unsigned* __restrict__ hm2s) {
    __shared__ float w1[16 * 64];
    __shared__ float w2[64 * 32];
    __shared__ float bb1[64];
    __shared__ float axs[16][17];
    __shared__ float h1s[16][65];
    int tid = threadIdx.x;
    for (int i = tid; i < 16 * 64; i += 256) w1[i] = W1[i];
    for (int i = tid; i < 64 * 32; i += 256) w2[i] = W2[i];
    if (tid < 64) bb1[tid] = b1[tid];

    int nl = tid >> 4, lane = tid & 15;
    int n = blockIdx.x * 16 + nl;

    if (lane < 8) {
        unsigned v = axb[n * 8 + lane];
        axs[nl][lane * 2]     = bflo(v);
        axs[nl][lane * 2 + 1] = bfhi(v);
    }
    __syncthreads();

    {
        int j0 = lane * 4;
        float h0 = bb1[j0], h1v = bb1[j0 + 1], h2 = bb1[j0 + 2], h3 = bb1[j0 + 3];
#pragma unroll
        for (int k = 0; k < 16; ++k) {
            float a = axs[nl][k];
            const float* wr = w1 + k * 64 + j0;
            h0 += a * wr[0]; h1v += a * wr[1]; h2 += a * wr[2]; h3 += a * wr[3];
        }
        h1s[nl][j0]     = fmaxf(h0, 0.f);
        h1s[nl][j0 + 1] = fmaxf(h1v, 0.f);
        h1s[nl][j0 + 2] = fmaxf(h2, 0.f);
        h1s[nl][j0 + 3] = fmaxf(h3, 0.f);
    }
    __syncthreads();

    {
        int j0 = lane * 2;
        float c0 = 0.f, c1 = 0.f;
#pragma unroll
        for (int k = 0; k < 64; ++k) {
            float hv = h1s[nl][k];
            c0 += hv * w2[k * 32 + j0];
            c1 += hv * w2[k * 32 + j0 + 1];
        }
        float di = dinv[n];
        hm2s[n * 16 + lane] = bf16pair(c0 * di, c1 * di);
    }
}

// ---------------- gather 2 + pool ----------------

__global__ void gather2_pool_kernel(const int* __restrict__ entries, const int* __restrict__ rowptr,
                                    const int* __restrict__ rowend, const float* __restrict__ dinv,
                                    const unsigned* __restrict__ hm2s, const float* __restrict__ b2,
                                    const int* __restrict__ batch,
                                    float* __restrict__ psum, float* __restrict__ pcnt) {
    int t = blockIdx.x * blockDim.x + threadIdx.x;
    int n = t >> 4, lane = t & 15;
    int beg = rowptr[n], end = rowend[n];
    unsigned self = hm2s[n * 16 + lane];
    float a0 = bflo(self), a1 = bfhi(self);
    for (int base = beg; base < end; base += 16) {
        int m = end - base; if (m > 16) m = 16;
        int s = (lane < m) ? __builtin_nontemporal_load(entries + base + lane) : 0;
        if (m == 16) {
#pragma unroll
            for (int j = 0; j < 16; ++j) {
                unsigned v = hm2s[__shfl(s, j, 16) * 16 + lane];
                a0 += bflo(v); a1 += bfhi(v);
            }
        } else {
            for (int j = 0; j < m; ++j) {
                unsigned v = hm2s[__shfl(s, j, 16) * 16 + lane];
                a0 += bflo(v); a1 += bfhi(v);
            }
        }
    }
    float di = dinv[n];
    int j0 = lane * 2;
    float v0 = fmaxf(a0 * di + b2[j0], 0.f);
    float v1 = fmaxf(a1 * di + b2[j0 + 1], 0.f);
    int g = batch[n];
    atomicAdd(&psum[g * 32 + j0], v0);
    atomicAdd(&psum[g * 32 + j0 + 1], v1);
    if (lane == 0) atomicAdd(&pcnt[g], 1.0f);
}

// ---------------- head ----------------

__global__ void head_kernel(const float* __restrict__ psum, const float* __restrict__ pcnt,
                            const float* __restrict__ fc1W, const float* __restrict__ fc1b,
                            const float* __restrict__ fc2W, const float* __restrict__ fc2b,
                            float* __restrict__ out) {
    int g = blockIdx.x * blockDim.x + threadIdx.x;
    if (g >= NGRAPHS) return;
    float inv = 1.0f / fmaxf(pcnt[g], 1.0f);
    float gv[32];
#pragma unroll
    for (int k = 0; k < 32; ++k) gv[k] = psum[g * 32 + k] * inv;
    float o = fc2b[0];
#pragma unroll
    for (int j = 0; j < 16; ++j) {
        float h = fc1b[j];
#pragma unroll
        for (int k = 0; k < 32; ++k) h += gv[k] * fc1W[k * 16 + j];
        h = fmaxf(h, 0.f);
        o += h * fc2W[j];
    }
    out[g] = 1.0f / (1.0f + expf(-o));
}

// ---------------- launch ----------------

extern "C" void kernel_launch(void* const* d_in, const int* in_sizes, int n_in,
                              void* d_out, int out_size, void* d_ws, size_t ws_size,
                              hipStream_t stream) {
    const float* x    = (const float*)d_in[0];
    const int*   ei   = (const int*)d_in[1];
    const int*   batch= (const int*)d_in[2];
    const float* W1   = (const float*)d_in[3];
    const float* b1   = (const float*)d_in[4];
    const float* W2   = (const float*)d_in[5];
    const float* b2   = (const float*)d_in[6];
    const float* fc1W = (const float*)d_in[7];
    const float* fc1b = (const float*)d_in[8];
    const float* fc2W = (const float*)d_in[9];
    const float* fc2b = (const float*)d_in[10];
    float* out = (float*)d_out;

    const int* src = ei;
    const int* dst = ei + NEDGES;

    char* wsb = (char*)d_ws;
    int*      bucketCur = (int*)wsb;                 // 2048 B (511 used)  } zeroed span
    float*    psum      = (float*)(wsb + 2048);      // 131072 B           }
    float*    pcnt      = (float*)(wsb + 133120);    // 4096 B             }  -> zero 137216 B
    int*      ebase     = (int*)(wsb + 137216);      // 2048 B
    float*    dinv      = (float*)(wsb + 139264);    // 400000 B
    int*      rowptr    = (int*)(wsb + 539264);      // 400000 B
    int*      rowend    = (int*)(wsb + 939264);      // 400000 B
    int*      stage     = (int*)(wsb + 1339392);     // 511*12288*4 = 25.1 MB
    int*      entries   = (int*)(wsb + 26456064);    // 12.8 MB
    unsigned* xs        = (unsigned*)(wsb + 39256064);  // 3.2 MB (bf16x2)
    unsigned* ax        = (unsigned*)(wsb + 42456064);  // 3.2 MB
    unsigned* hm2s      = (unsigned*)(wsb + 45656064);  // 6.4 MB (ends ~52.1 MB)

    const int B = 256;
    zero4_kernel<<<(8576 + B - 1) / B, B, 0, stream>>>((int4*)wsb, 8576);

    binA_kernel<<<NCHUNKS, B, 0, stream>>>(src, dst, bucketCur, stage);
    scanE_kernel<<<1, 64, 0, stream>>>(bucketCur, ebase);
    binB_kernel<<<NBUCK, B, 0, stream>>>(bucketCur, ebase, stage, (const float2*)x,
                                         entries, rowptr, rowend, dinv, xs);

    gather1_kernel<<<NNODES * 8 / B, B, 0, stream>>>(entries, rowptr, rowend, dinv, xs, ax);
    mlp_kernel<<<NNODES / 16, B, 0, stream>>>(ax, W1, b1, W2, dinv, hm2s);
    gather2_pool_kernel<<<NNODES * 16 / B, B, 0, stream>>>(entries, rowptr, rowend, dinv,
                                                           hm2s, b2, batch, psum, pcnt);
    head_kernel<<<(NGRAPHS + B - 1) / B, B, 0, stream>>>(psum, pcnt, fc1W, fc1b, fc2W, fc2b, out);
}

// Round 11
// 384.116 us; speedup vs baseline: 2.0010x; 1.0545x over previous
//
#include <hip/hip_runtime.h>
#include <math.h>

#define NNODES  100000
#define NEDGES  3200000
#define NGRAPHS 1024
#define BNODES  196                              // nodes per bucket
#define NBUCK   ((NNODES + BNODES - 1) / BNODES) // 511
#define SCAP    12288                            // staging capacity per bucket
#define CHUNK   8192
#define NCHUNKS ((NEDGES + CHUNK - 1) / CHUNK)   // 391

typedef int iv4 __attribute__((ext_vector_type(4)));

// ---- bf16x2 pack/unpack (RNE) ----
__device__ __forceinline__ unsigned bf16pair(float a, float b) {
    unsigned ua = __float_as_uint(a), ub = __float_as_uint(b);
    ua += 0x7fffu + ((ua >> 16) & 1u);
    ub += 0x7fffu + ((ub >> 16) & 1u);
    return (ua >> 16) | (ub & 0xffff0000u);
}
__device__ __forceinline__ float bflo(unsigned u) { return __uint_as_float(u << 16); }
__device__ __forceinline__ float bfhi(unsigned u) { return __uint_as_float(u & 0xffff0000u); }

// ---- fp8 e4m3 (OCP) manual pack/unpack; FTZ below 2^-6, saturate at 448 ----
__device__ __forceinline__ unsigned fp8_of(float v) {      // -> byte
    unsigned s = (__float_as_uint(v) >> 24) & 0x80u;
    float a = fminf(fabsf(v), 448.f);
    unsigned ub = __float_as_uint(a);
    unsigned lsb = (ub >> 20) & 1u;
    ub += 0x0007FFFFu + lsb;                 // RNE round into top-3 mantissa bits
    int em = (int)(ub >> 20) - (120 << 3);   // (e<<3|m) with fp8 bias
    if (em < 1) return s;                    // FTZ / zero
    if (em > 0x7E) em = 0x7E;                // clamp to 448
    return s | (unsigned)em;
}
__device__ __forceinline__ float fp8_to_f(unsigned b) {    // byte -> float
    unsigned em = b & 0x7Fu;
    unsigned s = (b & 0x80u) << 24;
    float f = __uint_as_float(s | ((em + 0x3C0u) << 20));
    return (em >= 8u) ? f : 0.f;             // FTZ denormals (|v|<2^-6; pre-scaled so negligible)
}

// ---------------- init ----------------

__global__ void zero4_kernel(int4* p, int nvec) {
    int i = blockIdx.x * blockDim.x + threadIdx.x;
    if (i < nvec) p[i] = make_int4(0, 0, 0, 0);
}

// ---------------- binA: coarse bucket sort of edges (coalesced staging writes) ----------------
// stage[b*SCAP + slot] = src | (dst - b*BNODES) << 17

__global__ void binA_kernel(const int* __restrict__ src, const int* __restrict__ dst,
                            int* __restrict__ bucketCur, int* __restrict__ stage) {
    __shared__ int lcnt[NBUCK + 1];
    int beg = blockIdx.x * CHUNK;
    int end = beg + CHUNK; if (end > NEDGES) end = NEDGES;
    for (int i = threadIdx.x; i < NBUCK; i += 256) lcnt[i] = 0;
    __syncthreads();
    for (int e = beg + threadIdx.x * 4; e < end; e += 1024) {
        iv4 d4 = __builtin_nontemporal_load((const iv4*)(dst + e));
        atomicAdd(&lcnt[d4.x / BNODES], 1);
        atomicAdd(&lcnt[d4.y / BNODES], 1);
        atomicAdd(&lcnt[d4.z / BNODES], 1);
        atomicAdd(&lcnt[d4.w / BNODES], 1);
    }
    __syncthreads();
    for (int b = threadIdx.x; b < NBUCK; b += 256) {
        int c = lcnt[b];
        lcnt[b] = (c > 0) ? atomicAdd(&bucketCur[b], c) : 0;
    }
    __syncthreads();
    for (int e = beg + threadIdx.x * 4; e < end; e += 1024) {
        iv4 d4 = __builtin_nontemporal_load((const iv4*)(dst + e));
        iv4 s4 = __builtin_nontemporal_load((const iv4*)(src + e));
        int b0 = d4.x / BNODES, b1 = d4.y / BNODES, b2 = d4.z / BNODES, b3 = d4.w / BNODES;
        stage[b0 * SCAP + atomicAdd(&lcnt[b0], 1)] = s4.x | ((d4.x - b0 * BNODES) << 17);
        stage[b1 * SCAP + atomicAdd(&lcnt[b1], 1)] = s4.y | ((d4.y - b1 * BNODES) << 17);
        stage[b2 * SCAP + atomicAdd(&lcnt[b2], 1)] = s4.z | ((d4.z - b2 * BNODES) << 17);
        stage[b3 * SCAP + atomicAdd(&lcnt[b3], 1)] = s4.w | ((d4.w - b3 * BNODES) << 17);
    }
}

// ---------------- scanE: exclusive scan over bucket counts ----------------

__global__ void scanE_kernel(const int* __restrict__ bucketCur, int* __restrict__ ebase) {
    int lane = threadIdx.x;          // 64 lanes
    int run = 0;
    for (int base = 0; base < NBUCK; base += 64) {
        int idx = base + lane;
        int own = (idx < NBUCK) ? bucketCur[idx] : 0;
        int v = own;
        for (int off = 1; off < 64; off <<= 1) {
            int t = __shfl_up(v, off, 64);
            if (lane >= off) v += t;
        }
        if (idx < NBUCK) ebase[idx] = run + v - own;
        run += __shfl(v, 63, 64);
    }
}

// ---------------- binB: per-bucket fine sort + rowptr/rowend/dinv/xs ----------------

__global__ void binB_kernel(const int* __restrict__ bucketCur, const int* __restrict__ ebase,
                            const int* __restrict__ stage, const float2* __restrict__ x,
                            int* __restrict__ entries, int* __restrict__ rowptr,
                            int* __restrict__ rowend, float* __restrict__ dinv,
                            unsigned* __restrict__ xs) {
    __shared__ int s[256];
    __shared__ int ncur[256];
    __shared__ float ndinv[256];
    int b = blockIdx.x;
    int cntE = bucketCur[b];
    int eb = ebase[b];
    int nlo = b * BNODES;
    int nn = NNODES - nlo; if (nn > BNODES) nn = BNODES;
    int sb = b * SCAP;
    int tid = threadIdx.x;

    s[tid] = 0;
    __syncthreads();
    for (int e = tid; e < cntE; e += 256) {
        unsigned w = (unsigned)stage[sb + e];
        atomicAdd(&s[w >> 17], 1);
    }
    __syncthreads();
    int v = s[tid];
    for (int off = 1; off < 256; off <<= 1) {
        int t = (tid >= off) ? s[tid - off] : 0;
        __syncthreads();
        s[tid] += t;
        __syncthreads();
    }
    int excl = s[tid] - v;
    ncur[tid] = excl;
    if (tid < nn) {
        rowptr[nlo + tid] = eb + excl;
        rowend[nlo + tid] = eb + excl + v;
        float di = rsqrtf((float)(v + 1));   // +1 self-loop
        dinv[nlo + tid] = di;
        ndinv[tid] = di;
    }
    __syncthreads();
    for (int i = tid; i < nn * 8; i += 256) {
        int node = i >> 3, w = i & 7;
        float2 v2 = x[(size_t)(nlo + node) * 8 + w];
        float di = ndinv[node];
        xs[(nlo + node) * 8 + w] = bf16pair(v2.x * di, v2.y * di);
    }
    for (int e = tid; e < cntE; e += 256) {
        unsigned w = (unsigned)stage[sb + e];
        int dl = w >> 17;
        int slot = atomicAdd(&ncur[dl], 1);
        entries[eb + slot] = (int)(w & 0x1FFFFu);
    }
}

// ---------------- gather 1 (bf16, 8 lanes/node, 2 feats/lane) ----------------

__global__ void gather1_kernel(const int* __restrict__ entries, const int* __restrict__ rowptr,
                               const int* __restrict__ rowend, const float* __restrict__ dinv,
                               const unsigned* __restrict__ xs, unsigned* __restrict__ ax) {
    int t = blockIdx.x * blockDim.x + threadIdx.x;
    int n = t >> 3, lane = t & 7;
    int beg = rowptr[n], end = rowend[n];
    unsigned self = xs[n * 8 + lane];
    float a0 = bflo(self), a1 = bfhi(self);
    for (int base = beg; base < end; base += 8) {
        int m = end - base; if (m > 8) m = 8;
        int s = (lane < m) ? __builtin_nontemporal_load(entries + base + lane) : 0;
        if (m == 8) {
#pragma unroll
            for (int j = 0; j < 8; ++j) {
                unsigned v = xs[__shfl(s, j, 8) * 8 + lane];
                a0 += bflo(v); a1 += bfhi(v);
            }
        } else {
            for (int j = 0; j < m; ++j) {
                unsigned v = xs[__shfl(s, j, 8) * 8 + lane];
                a0 += bflo(v); a1 += bfhi(v);
            }
        }
    }
    float di = dinv[n];
    ax[n * 8 + lane] = bf16pair(a0 * di, a1 * di);
}

// ---------------- fused node MLP: ax -> relu(axW1+b1) -> (h1W2)*dinv*64 -> fp8 hm2f ----------------

__global__ void mlp_kernel(const unsigned* __restrict__ axb, const float* __restrict__ W1,
                           const float* __restrict__ b1, const float* __restrict__ W2,
                           const float* __restrict__ dinv, unsigned short* __restrict__ hm2f) {
    __shared__ float w1[16 * 64];
    __shared__ float w2[64 * 32];
    __shared__ float bb1[64];
    __shared__ float axs[16][17];
    __shared__ float h1s[16][65];
    int tid = threadIdx.x;
    for (int i = tid; i < 16 * 64; i += 256) w1[i] = W1[i];
    for (int i = tid; i < 64 * 32; i += 256) w2[i] = W2[i];
    if (tid < 64) bb1[tid] = b1[tid];

    int nl = tid >> 4, lane = tid & 15;
    int n = blockIdx.x * 16 + nl;

    if (lane < 8) {
        unsigned v = axb[n * 8 + lane];
        axs[nl][lane * 2]     = bflo(v);
        axs[nl][lane * 2 + 1] = bfhi(v);
    }
    __syncthreads();

    {
        int j0 = lane * 4;
        float h0 = bb1[j0], h1v = bb1[j0 + 1], h2 = bb1[j0 + 2], h3 = bb1[j0 + 3];
#pragma unroll
        for (int k = 0; k < 16; ++k) {
            float a = axs[nl][k];
            const float* wr = w1 + k * 64 + j0;
            h0 += a * wr[0]; h1v += a * wr[1]; h2 += a * wr[2]; h3 += a * wr[3];
        }
        h1s[nl][j0]     = fmaxf(h0, 0.f);
        h1s[nl][j0 + 1] = fmaxf(h1v, 0.f);
        h1s[nl][j0 + 2] = fmaxf(h2, 0.f);
        h1s[nl][j0 + 3] = fmaxf(h3, 0.f);
    }
    __syncthreads();

    {
        int j0 = lane * 2;
        float c0 = 0.f, c1 = 0.f;
#pragma unroll
        for (int k = 0; k < 64; ++k) {
            float hv = h1s[nl][k];
            c0 += hv * w2[k * 32 + j0];
            c1 += hv * w2[k * 32 + j0 + 1];
        }
        float sc = dinv[n] * 64.f;              // x64 pre-scale for fp8
        unsigned b0 = fp8_of(c0 * sc), b1v = fp8_of(c1 * sc);
        hm2f[n * 16 + lane] = (unsigned short)(b0 | (b1v << 8));
    }
}

// ---------------- gather 2 + pool (fp8 rows, 8 lanes/node, 4 feats/lane) ----------------

__global__ void gather2_pool_kernel(const int* __restrict__ entries, const int* __restrict__ rowptr,
                                    const int* __restrict__ rowend, const float* __restrict__ dinv,
                                    const unsigned* __restrict__ hm2f, const float4* __restrict__ b2,
                                    const int* __restrict__ batch,
                                    float* __restrict__ psum, float* __restrict__ pcnt) {
    int t = blockIdx.x * blockDim.x + threadIdx.x;
    int n = t >> 3, lane = t & 7;
    int beg = rowptr[n], end = rowend[n];
    unsigned self = hm2f[n * 8 + lane];
    float a0 = fp8_to_f(self & 0xFFu), a1 = fp8_to_f((self >> 8) & 0xFFu);
    float a2 = fp8_to_f((self >> 16) & 0xFFu), a3 = fp8_to_f(self >> 24);
    for (int base = beg; base < end; base += 8) {
        int m = end - base; if (m > 8) m = 8;
        int s = (lane < m) ? __builtin_nontemporal_load(entries + base + lane) : 0;
        if (m == 8) {
#pragma unroll
            for (int j = 0; j < 8; ++j) {
                unsigned v = hm2f[__shfl(s, j, 8) * 8 + lane];
                a0 += fp8_to_f(v & 0xFFu);
                a1 += fp8_to_f((v >> 8) & 0xFFu);
                a2 += fp8_to_f((v >> 16) & 0xFFu);
                a3 += fp8_to_f(v >> 24);
            }
        } else {
            for (int j = 0; j < m; ++j) {
                unsigned v = hm2f[__shfl(s, j, 8) * 8 + lane];
                a0 += fp8_to_f(v & 0xFFu);
                a1 += fp8_to_f((v >> 8) & 0xFFu);
                a2 += fp8_to_f((v >> 16) & 0xFFu);
                a3 += fp8_to_f(v >> 24);
            }
        }
    }
    float sc = dinv[n] * (1.0f / 64.f);         // undo x64 pre-scale
    float4 bb = b2[lane];
    float v0 = fmaxf(a0 * sc + bb.x, 0.f);
    float v1 = fmaxf(a1 * sc + bb.y, 0.f);
    float v2 = fmaxf(a2 * sc + bb.z, 0.f);
    float v3 = fmaxf(a3 * sc + bb.w, 0.f);
    int g = batch[n];
    float* pg = psum + g * 32 + lane * 4;
    atomicAdd(pg + 0, v0);
    atomicAdd(pg + 1, v1);
    atomicAdd(pg + 2, v2);
    atomicAdd(pg + 3, v3);
    if (lane == 0) atomicAdd(&pcnt[g], 1.0f);
}

// ---------------- head ----------------

__global__ void head_kernel(const float* __restrict__ psum, const float* __restrict__ pcnt,
                            const float* __restrict__ fc1W, const float* __restrict__ fc1b,
                            const float* __restrict__ fc2W, const float* __restrict__ fc2b,
                            float* __restrict__ out) {
    int g = blockIdx.x * blockDim.x + threadIdx.x;
    if (g >= NGRAPHS) return;
    float inv = 1.0f / fmaxf(pcnt[g], 1.0f);
    float gv[32];
#pragma unroll
    for (int k = 0; k < 32; ++k) gv[k] = psum[g * 32 + k] * inv;
    float o = fc2b[0];
#pragma unroll
    for (int j = 0; j < 16; ++j) {
        float h = fc1b[j];
#pragma unroll
        for (int k = 0; k < 32; ++k) h += gv[k] * fc1W[k * 16 + j];
        h = fmaxf(h, 0.f);
        o += h * fc2W[j];
    }
    out[g] = 1.0f / (1.0f + expf(-o));
}

// ---------------- launch ----------------

extern "C" void kernel_launch(void* const* d_in, const int* in_sizes, int n_in,
                              void* d_out, int out_size, void* d_ws, size_t ws_size,
                              hipStream_t stream) {
    const float* x    = (const float*)d_in[0];
    const int*   ei   = (const int*)d_in[1];
    const int*   batch= (const int*)d_in[2];
    const float* W1   = (const float*)d_in[3];
    const float* b1   = (const float*)d_in[4];
    const float* W2   = (const float*)d_in[5];
    const float* b2   = (const float*)d_in[6];
    const float* fc1W = (const float*)d_in[7];
    const float* fc1b = (const float*)d_in[8];
    const float* fc2W = (const float*)d_in[9];
    const float* fc2b = (const float*)d_in[10];
    float* out = (float*)d_out;

    const int* src = ei;
    const int* dst = ei + NEDGES;

    char* wsb = (char*)d_ws;
    int*      bucketCur = (int*)wsb;                 // 2048 B  } zeroed span
    float*    psum      = (float*)(wsb + 2048);      // 131072  }
    float*    pcnt      = (float*)(wsb + 133120);    // 4096    }  -> zero 137216 B
    int*      ebase     = (int*)(wsb + 137216);      // 2048
    float*    dinv      = (float*)(wsb + 139264);    // 400000
    int*      rowptr    = (int*)(wsb + 539264);      // 400000
    int*      rowend    = (int*)(wsb + 939264);      // 400000
    int*      stage     = (int*)(wsb + 1339392);     // 25.1 MB
    int*      entries   = (int*)(wsb + 26456064);    // 12.8 MB
    unsigned* xs        = (unsigned*)(wsb + 39256064);        // 3.2 MB (bf16x2)
    unsigned* ax        = (unsigned*)(wsb + 42456064);        // 3.2 MB
    unsigned short* hm2f= (unsigned short*)(wsb + 45656064);  // 3.2 MB (fp8, 32 B rows)

    const int B = 256;
    zero4_kernel<<<(8576 + B - 1) / B, B, 0, stream>>>((int4*)wsb, 8576);

    binA_kernel<<<NCHUNKS, B, 0, stream>>>(src, dst, bucketCur, stage);
    scanE_kernel<<<1, 64, 0, stream>>>(bucketCur, ebase);
    binB_kernel<<<NBUCK, B, 0, stream>>>(bucketCur, ebase, stage, (const float2*)x,
                                         entries, rowptr, rowend, dinv, xs);

    gather1_kernel<<<NNODES * 8 / B, B, 0, stream>>>(entries, rowptr, rowend, dinv, xs, ax);
    mlp_kernel<<<NNODES / 16, B, 0, stream>>>(ax, W1, b1, W2, dinv, hm2f);
    gather2_pool_kernel<<<NNODES * 8 / B, B, 0, stream>>>(entries, rowptr, rowend, dinv,
                                                          (const unsigned*)hm2f, (const float4*)b2,
                                                          batch, psum, pcnt);
    head_kernel<<<(NGRAPHS + B - 1) / B, B, 0, stream>>>(psum, pcnt, fc1W, fc1b, fc2W, fc2b, out);
}